// Round 1
// baseline (121.779 us; speedup 1.0000x reference)
//
#include <hip/hip_runtime.h>
#include <math.h>

#define HH 64
#define WW 64
#define CC 256
#define NHEAD 8
#define HD 32
#define KW 7
#define NPIX (HH * WW)

// C[M,N] = A[M,K] @ B[N,K]^T + bias[N]   (nn.Linear semantics)
// BM=BN=64, BK=16, 256 threads, 4x4 per thread.
__global__ __launch_bounds__(256) void gemm_nt_bias(
    const float* __restrict__ A, const float* __restrict__ B,
    const float* __restrict__ bias, float* __restrict__ Cd,
    int M, int N, int Kd) {
  __shared__ float As[16][68];
  __shared__ float Bs[16][68];

  const int t  = threadIdx.x;
  const int tx = t & 15;      // output col group
  const int ty = t >> 4;      // output row group
  const int bm = blockIdx.x * 64;
  const int bn = blockIdx.y * 64;

  const int lr = t >> 2;  // 0..63 tile row for loads
  const int lq = t & 3;   // which float4 along K (BK=16)

  float acc[4][4] = {};

  for (int kt = 0; kt < Kd; kt += 16) {
    float4 av = *(const float4*)(A + (size_t)(bm + lr) * Kd + kt + lq * 4);
    float4 bv = *(const float4*)(B + (size_t)(bn + lr) * Kd + kt + lq * 4);
    As[lq * 4 + 0][lr] = av.x;
    As[lq * 4 + 1][lr] = av.y;
    As[lq * 4 + 2][lr] = av.z;
    As[lq * 4 + 3][lr] = av.w;
    Bs[lq * 4 + 0][lr] = bv.x;
    Bs[lq * 4 + 1][lr] = bv.y;
    Bs[lq * 4 + 2][lr] = bv.z;
    Bs[lq * 4 + 3][lr] = bv.w;
    __syncthreads();
#pragma unroll
    for (int kk = 0; kk < 16; ++kk) {
      float4 a = *(const float4*)&As[kk][ty * 4];
      float4 b = *(const float4*)&Bs[kk][tx * 4];
      float ar[4] = {a.x, a.y, a.z, a.w};
      float br[4] = {b.x, b.y, b.z, b.w};
#pragma unroll
      for (int ii = 0; ii < 4; ++ii)
#pragma unroll
        for (int jj = 0; jj < 4; ++jj) acc[ii][jj] = fmaf(ar[ii], br[jj], acc[ii][jj]);
    }
    __syncthreads();
  }

#pragma unroll
  for (int ii = 0; ii < 4; ++ii) {
    const int row = bm + ty * 4 + ii;
    const int col = bn + tx * 4;
    float4 o;
    o.x = acc[ii][0] + bias[col + 0];
    o.y = acc[ii][1] + bias[col + 1];
    o.z = acc[ii][2] + bias[col + 2];
    o.w = acc[ii][3] + bias[col + 3];
    *(float4*)(Cd + (size_t)row * N + col) = o;
  }
}

// One block (256 thr) per pixel: thread t -> head = t>>5, d = t&31.
// qkv layout per pixel: [3][NHEAD][HD] = 768 floats (q:0, k:256, v:512).
__global__ __launch_bounds__(256) void natten_kernel(
    const float* __restrict__ qkv, const float* __restrict__ rpb,
    float* __restrict__ aout) {
  const int pix  = blockIdx.x;
  const int i    = pix >> 6;
  const int j    = pix & 63;
  const int t    = threadIdx.x;
  const int head = t >> 5;
  const int d    = t & 31;

  const int si = min(max(i - 3, 0), HH - KW);
  const int sj = min(max(j - 3, 0), WW - KW);
  const float scale = 0.17677669529663687f;  // 1/sqrt(32)

  __shared__ float sm[NHEAD][56];

  const float q = qkv[(size_t)pix * 768 + head * HD + d] * scale;

  // QK^T + bias -> logits in LDS
#pragma unroll
  for (int a = 0; a < KW; ++a) {
    const int ni = si + a;
    const int bi = ni - i + (KW - 1);
#pragma unroll
    for (int c = 0; c < KW; ++c) {
      const int nj   = sj + c;
      const int npix = ni * WW + nj;
      float p = q * qkv[(size_t)npix * 768 + 256 + t];
      p += __shfl_xor(p, 16, 32);
      p += __shfl_xor(p, 8, 32);
      p += __shfl_xor(p, 4, 32);
      p += __shfl_xor(p, 2, 32);
      p += __shfl_xor(p, 1, 32);
      if (d == 0) {
        const int bj = nj - j + (KW - 1);
        sm[head][a * KW + c] = p + rpb[head * 169 + bi * 13 + bj];
      }
    }
  }
  __syncthreads();

  // softmax over 49 logits, computed redundantly by each head's 32 lanes
  float l0 = sm[head][d];
  float l1 = (d < 17) ? sm[head][d + 32] : -INFINITY;
  float m  = fmaxf(l0, l1);
#pragma unroll
  for (int off = 16; off; off >>= 1) m = fmaxf(m, __shfl_xor(m, off, 32));
  float e0 = __expf(l0 - m);
  float e1 = (d < 17) ? __expf(l1 - m) : 0.f;
  float s  = e0 + e1;
#pragma unroll
  for (int off = 16; off; off >>= 1) s += __shfl_xor(s, off, 32);
  const float inv = 1.f / s;
  sm[head][d] = e0 * inv;
  if (d < 17) sm[head][d + 32] = e1 * inv;
  __syncthreads();

  // PV
  float acc = 0.f;
#pragma unroll
  for (int a = 0; a < KW; ++a) {
    const int ni = si + a;
#pragma unroll
    for (int c = 0; c < KW; ++c) {
      const int nj   = sj + c;
      const int npix = ni * WW + nj;
      acc = fmaf(sm[head][a * KW + c], qkv[(size_t)npix * 768 + 512 + t], acc);
    }
  }
  aout[(size_t)pix * CC + t] = acc;
}

extern "C" void kernel_launch(void* const* d_in, const int* in_sizes, int n_in,
                              void* d_out, int out_size, void* d_ws, size_t ws_size,
                              hipStream_t stream) {
  const float* x      = (const float*)d_in[0];  // [4096, 256]
  const float* qkv_w  = (const float*)d_in[1];  // [768, 256]
  const float* qkv_b  = (const float*)d_in[2];  // [768]
  const float* proj_w = (const float*)d_in[3];  // [256, 256]
  const float* proj_b = (const float*)d_in[4];  // [256]
  const float* rpb    = (const float*)d_in[5];  // [8, 13, 13]
  float* out = (float*)d_out;                   // [4096, 256]

  float* qkv  = (float*)d_ws;                   // [4096, 768] = 12.6 MB
  float* aout = qkv + (size_t)NPIX * 768;       // [4096, 256] = 4 MB

  // 1) QKV projection: [4096,256] @ [768,256]^T -> [4096,768]
  gemm_nt_bias<<<dim3(NPIX / 64, 768 / 64), 256, 0, stream>>>(
      x, qkv_w, qkv_b, qkv, NPIX, 768, CC);

  // 2) Neighborhood attention -> [4096,256]
  natten_kernel<<<NPIX, 256, 0, stream>>>(qkv, rpb, aout);

  // 3) Output projection: [4096,256] @ [256,256]^T -> [4096,256]
  gemm_nt_bias<<<dim3(NPIX / 64, CC / 64), 256, 0, stream>>>(
      aout, proj_w, proj_b, out, NPIX, CC, CC);
}

// Round 2
// 62.997 us; speedup vs baseline: 1.9331x; 1.9331x over previous
//
#include <hip/hip_runtime.h>
#include <math.h>

#define HH 64
#define WW 64
#define CC 256
#define NHEAD 8
#define HD 32
#define KW 7
#define NPIX (HH * WW)

#define HALO 14
#define NROW (HALO * HALO)  // 196
#define KST 36              // K/V LDS row stride in floats (144B, 16B-aligned)
#define PST 53              // probs LDS row stride

// ---------------- GEMM: C[M,N] = A[M,K] @ B[N,K]^T + bias[N] ----------------
__global__ __launch_bounds__(256) void gemm_nt_bias(
    const float* __restrict__ A, const float* __restrict__ B,
    const float* __restrict__ bias, float* __restrict__ Cd,
    int M, int N, int Kd) {
  __shared__ float As[16][68];
  __shared__ float Bs[16][68];

  const int t  = threadIdx.x;
  const int tx = t & 15;
  const int ty = t >> 4;
  const int bm = blockIdx.x * 64;
  const int bn = blockIdx.y * 64;

  const int lr = t >> 2;
  const int lq = t & 3;

  float acc[4][4] = {};

  for (int kt = 0; kt < Kd; kt += 16) {
    float4 av = *(const float4*)(A + (size_t)(bm + lr) * Kd + kt + lq * 4);
    float4 bv = *(const float4*)(B + (size_t)(bn + lr) * Kd + kt + lq * 4);
    As[lq * 4 + 0][lr] = av.x;
    As[lq * 4 + 1][lr] = av.y;
    As[lq * 4 + 2][lr] = av.z;
    As[lq * 4 + 3][lr] = av.w;
    Bs[lq * 4 + 0][lr] = bv.x;
    Bs[lq * 4 + 1][lr] = bv.y;
    Bs[lq * 4 + 2][lr] = bv.z;
    Bs[lq * 4 + 3][lr] = bv.w;
    __syncthreads();
#pragma unroll
    for (int kk = 0; kk < 16; ++kk) {
      float4 a = *(const float4*)&As[kk][ty * 4];
      float4 b = *(const float4*)&Bs[kk][tx * 4];
      float ar[4] = {a.x, a.y, a.z, a.w};
      float br[4] = {b.x, b.y, b.z, b.w};
#pragma unroll
      for (int ii = 0; ii < 4; ++ii)
#pragma unroll
        for (int jj = 0; jj < 4; ++jj) acc[ii][jj] = fmaf(ar[ii], br[jj], acc[ii][jj]);
    }
    __syncthreads();
  }

#pragma unroll
  for (int ii = 0; ii < 4; ++ii) {
    const int row = bm + ty * 4 + ii;
    const int col = bn + tx * 4;
    float4 o;
    o.x = acc[ii][0] + bias[col + 0];
    o.y = acc[ii][1] + bias[col + 1];
    o.z = acc[ii][2] + bias[col + 2];
    o.w = acc[ii][3] + bias[col + 3];
    *(float4*)(Cd + (size_t)row * N + col) = o;
  }
}

// ---------------- Tiled neighborhood attention ----------------
// grid: (64 tiles of 8x8 pixels, 8 heads). block: 256 threads = 64 pixels x 4.
// LDS: K/V halo (14x14 rows x 32 dims, stride 36) + probs + rpb slice.
__global__ __launch_bounds__(256) void natten2(
    const float* __restrict__ qkv, const float* __restrict__ rpb,
    float* __restrict__ aout) {
  const int head = blockIdx.y;
  const int tile = blockIdx.x;
  const int ti = tile >> 3, tj = tile & 7;
  const int i0 = ti * 8, j0 = tj * 8;
  const int hs = min(max(i0 - 3, 0), HH - HALO);  // halo origin row
  const int ws = min(max(j0 - 3, 0), WW - HALO);  // halo origin col

  __shared__ float Ks[NROW][KST];
  __shared__ float Vs[NROW][KST];
  __shared__ float Ps[64][PST];
  __shared__ float Rs[169];

  const int t = threadIdx.x;

  if (t < 169) Rs[t] = rpb[head * 169 + t];

  // ---- stage K,V halo: 392 row-tasks (196 K + 196 V), 8 lanes x float4 each
  {
    const int lane8 = t & 7;
    const int rt0   = t >> 3;  // 0..31
#pragma unroll
    for (int it = 0; it < 13; ++it) {
      const int task = it * 32 + rt0;
      if (task < 2 * NROW) {
        const int mat = (task >= NROW) ? 1 : 0;
        const int row = task - mat * NROW;
        const int hr  = row / HALO;
        const int hc  = row - hr * HALO;
        const int g   = (hs + hr) * WW + (ws + hc);
        const float4 v = *(const float4*)(qkv + (size_t)g * 768 + 256 + mat * 256 +
                                          head * HD + lane8 * 4);
        float* dst = mat ? &Vs[row][lane8 * 4] : &Ks[row][lane8 * 4];
        *(float4*)dst = v;
      }
    }
  }
  __syncthreads();

  // ---- QK^T + bias -> softmax -> probs in LDS
  const int p  = t >> 2;  // pixel in tile, same-wave 4-lane groups
  const int tp = t & 3;
  const int pi = p >> 3, pj = p & 7;
  const int i = i0 + pi, j = j0 + pj;
  const int si = min(max(i - 3, 0), HH - KW);
  const int sj = min(max(j - 3, 0), WW - KW);
  const int lr0 = si - hs, lc0 = sj - ws;
  const int bi0 = si - i + (KW - 1);
  const int bj0 = sj - j + (KW - 1);

  float4 q[8];
  {
    const float* qp = qkv + (size_t)(i * WW + j) * 768 + head * HD;
#pragma unroll
    for (int z = 0; z < 8; ++z) q[z] = *(const float4*)(qp + z * 4);
  }

  const float scale = 0.17677669529663687f;  // 1/sqrt(32)
  const int nbeg = tp * 13;

  float lg[13];
#pragma unroll
  for (int z = 0; z < 13; ++z) lg[z] = -INFINITY;

#pragma unroll
  for (int z = 0; z < 13; ++z) {
    const int n = nbeg + z;
    if (n < KW * KW) {
      const int a = n / KW;
      const int c = n - a * KW;
      const int krow = (lr0 + a) * HALO + (lc0 + c);
      const float* kp = &Ks[krow][0];
      float s = 0.f;
#pragma unroll
      for (int zz = 0; zz < 8; ++zz) {
        const float4 kv = *(const float4*)(kp + zz * 4);
        s = fmaf(q[zz].x, kv.x, s);
        s = fmaf(q[zz].y, kv.y, s);
        s = fmaf(q[zz].z, kv.z, s);
        s = fmaf(q[zz].w, kv.w, s);
      }
      lg[z] = s * scale + Rs[(bi0 + a) * 13 + (bj0 + c)];
    }
  }

  float m = -INFINITY;
#pragma unroll
  for (int z = 0; z < 13; ++z) m = fmaxf(m, lg[z]);
  m = fmaxf(m, __shfl_xor(m, 1, 4));
  m = fmaxf(m, __shfl_xor(m, 2, 4));

  float ssum = 0.f;
#pragma unroll
  for (int z = 0; z < 13; ++z) {
    const float e = __expf(lg[z] - m);  // exp(-inf)=0 for padding
    lg[z] = e;
    ssum += e;
  }
  ssum += __shfl_xor(ssum, 1, 4);
  ssum += __shfl_xor(ssum, 2, 4);
  const float inv = 1.f / ssum;

#pragma unroll
  for (int z = 0; z < 13; ++z) {
    const int n = nbeg + z;
    if (n < KW * KW) Ps[p][n] = lg[z] * inv;
  }
  __syncthreads();

  // ---- PV: thread owns 8 output dims, iterates all 49 neighbors
  const int d0 = tp * 8;
  float4 o0 = {0.f, 0.f, 0.f, 0.f};
  float4 o1 = {0.f, 0.f, 0.f, 0.f};
#pragma unroll
  for (int a = 0; a < KW; ++a) {
    const int rbase = (lr0 + a) * HALO + lc0;
#pragma unroll
    for (int c = 0; c < KW; ++c) {
      const float pr = Ps[p][a * KW + c];
      const float* vp = &Vs[rbase + c][d0];
      const float4 va = *(const float4*)(vp);
      const float4 vb = *(const float4*)(vp + 4);
      o0.x = fmaf(pr, va.x, o0.x);
      o0.y = fmaf(pr, va.y, o0.y);
      o0.z = fmaf(pr, va.z, o0.z);
      o0.w = fmaf(pr, va.w, o0.w);
      o1.x = fmaf(pr, vb.x, o1.x);
      o1.y = fmaf(pr, vb.y, o1.y);
      o1.z = fmaf(pr, vb.z, o1.z);
      o1.w = fmaf(pr, vb.w, o1.w);
    }
  }

  float* op = aout + (size_t)(i * WW + j) * CC + head * HD + d0;
  *(float4*)op       = o0;
  *(float4*)(op + 4) = o1;
}

extern "C" void kernel_launch(void* const* d_in, const int* in_sizes, int n_in,
                              void* d_out, int out_size, void* d_ws, size_t ws_size,
                              hipStream_t stream) {
  const float* x      = (const float*)d_in[0];
  const float* qkv_w  = (const float*)d_in[1];
  const float* qkv_b  = (const float*)d_in[2];
  const float* proj_w = (const float*)d_in[3];
  const float* proj_b = (const float*)d_in[4];
  const float* rpb    = (const float*)d_in[5];
  float* out = (float*)d_out;

  float* qkv  = (float*)d_ws;              // [4096, 768]
  float* aout = qkv + (size_t)NPIX * 768;  // [4096, 256]

  gemm_nt_bias<<<dim3(NPIX / 64, 768 / 64), 256, 0, stream>>>(
      x, qkv_w, qkv_b, qkv, NPIX, 768, CC);

  natten2<<<dim3(64, NHEAD), 256, 0, stream>>>(qkv, rpb, aout);

  gemm_nt_bias<<<dim3(NPIX / 64, CC / 64), 256, 0, stream>>>(
      aout, proj_w, proj_b, out, NPIX, CC, CC);
}

// Round 3
// 53.123 us; speedup vs baseline: 2.2924x; 1.1859x over previous
//
#include <hip/hip_runtime.h>
#include <math.h>

#define HH 64
#define WW 64
#define CC 256
#define NHEAD 8
#define HD 32
#define KW 7
#define NPIX (HH * WW)

#define HALO 14
#define NROW (HALO * HALO)  // 196
#define KST 36
#define PST 53

typedef short short8v __attribute__((ext_vector_type(8)));
typedef float float4v __attribute__((ext_vector_type(4)));

__device__ __forceinline__ ushort f2bf(float f) {
  union { float f; unsigned u; } c;
  c.f = f;
  unsigned u = c.u;
  return (ushort)((u + 0x7FFFu + ((u >> 16) & 1u)) >> 16);
}

// ---------------- f32 -> bf16 conversion for x, qkv_w, proj_w ----------------
// float4-granular: x = 262144 f4, qkv_w = 49152 f4, proj_w = 16384 f4.
__global__ __launch_bounds__(256) void convert_all(
    const float* __restrict__ x, const float* __restrict__ qw,
    const float* __restrict__ pw, ushort* __restrict__ xb,
    ushort* __restrict__ qwb, ushort* __restrict__ pwb) {
  const int i4 = blockIdx.x * 256 + threadIdx.x;
  const float* src;
  ushort* dst;
  int o4;
  if (i4 < 262144) {
    src = x; dst = xb; o4 = i4;
  } else if (i4 < 262144 + 49152) {
    src = qw; dst = qwb; o4 = i4 - 262144;
  } else {
    src = pw; dst = pwb; o4 = i4 - (262144 + 49152);
  }
  const float4 v = *(const float4*)(src + (size_t)o4 * 4);
  ushort4 o;
  o.x = f2bf(v.x); o.y = f2bf(v.y); o.z = f2bf(v.z); o.w = f2bf(v.w);
  *(ushort4*)(dst + (size_t)o4 * 4) = o;
}

// ---------------- bf16 MFMA GEMM: C[M,N] = A[M,256] @ B[N,256]^T + bias ------
// grid (M/64, N/64), 256 thr = 4 waves, each wave a 32x32 sub-tile.
// Fragments loaded directly from global (L2-resident), no LDS.
template <int N>
__global__ __launch_bounds__(256) void gemm_mfma(
    const ushort* __restrict__ A, const ushort* __restrict__ B,
    const float* __restrict__ bias, float* __restrict__ Cd) {
  const int t = threadIdx.x;
  const int lane = t & 63;
  const int wave = t >> 6;
  const int wr = (wave >> 1) * 32;
  const int wc = (wave & 1) * 32;
  const int bm = blockIdx.x * 64;
  const int bn = blockIdx.y * 64;

  const int lrow = lane & 15;
  const int lk   = (lane >> 4) * 8;

  const ushort* Ab = A + (size_t)(bm + wr + lrow) * 256 + lk;
  const ushort* Bb = B + (size_t)(bn + wc + lrow) * 256 + lk;

  float4v acc[2][2] = {{{0.f, 0.f, 0.f, 0.f}, {0.f, 0.f, 0.f, 0.f}},
                       {{0.f, 0.f, 0.f, 0.f}, {0.f, 0.f, 0.f, 0.f}}};

#pragma unroll
  for (int kt = 0; kt < 256; kt += 32) {
    const short8v a0 = *(const short8v*)(Ab + kt);
    const short8v a1 = *(const short8v*)(Ab + kt + 16 * 256);
    const short8v b0 = *(const short8v*)(Bb + kt);
    const short8v b1 = *(const short8v*)(Bb + kt + 16 * 256);
    acc[0][0] = __builtin_amdgcn_mfma_f32_16x16x32_bf16(a0, b0, acc[0][0], 0, 0, 0);
    acc[0][1] = __builtin_amdgcn_mfma_f32_16x16x32_bf16(a0, b1, acc[0][1], 0, 0, 0);
    acc[1][0] = __builtin_amdgcn_mfma_f32_16x16x32_bf16(a1, b0, acc[1][0], 0, 0, 0);
    acc[1][1] = __builtin_amdgcn_mfma_f32_16x16x32_bf16(a1, b1, acc[1][1], 0, 0, 0);
  }

#pragma unroll
  for (int bi = 0; bi < 2; ++bi) {
#pragma unroll
    for (int bj = 0; bj < 2; ++bj) {
      const int n  = bn + wc + bj * 16 + lrow;
      const float bv = bias[n];
      const int m0 = bm + wr + bi * 16 + (lane >> 4) * 4;
#pragma unroll
      for (int r = 0; r < 4; ++r)
        Cd[(size_t)(m0 + r) * N + n] = acc[bi][bj][r] + bv;
    }
  }
}

// ---------------- Tiled neighborhood attention (bf16 output) ----------------
__global__ __launch_bounds__(256) void natten2(
    const float* __restrict__ qkv, const float* __restrict__ rpb,
    ushort* __restrict__ aoutb) {
  const int head = blockIdx.y;
  const int tile = blockIdx.x;
  const int ti = tile >> 3, tj = tile & 7;
  const int i0 = ti * 8, j0 = tj * 8;
  const int hs = min(max(i0 - 3, 0), HH - HALO);
  const int ws = min(max(j0 - 3, 0), WW - HALO);

  __shared__ float Ks[NROW][KST];
  __shared__ float Vs[NROW][KST];
  __shared__ float Ps[64][PST];
  __shared__ float Rs[169];

  const int t = threadIdx.x;

  if (t < 169) Rs[t] = rpb[head * 169 + t];

  {
    const int lane8 = t & 7;
    const int rt0   = t >> 3;
#pragma unroll
    for (int it = 0; it < 13; ++it) {
      const int task = it * 32 + rt0;
      if (task < 2 * NROW) {
        const int mat = (task >= NROW) ? 1 : 0;
        const int row = task - mat * NROW;
        const int hr  = row / HALO;
        const int hc  = row - hr * HALO;
        const int g   = (hs + hr) * WW + (ws + hc);
        const float4 v = *(const float4*)(qkv + (size_t)g * 768 + 256 + mat * 256 +
                                          head * HD + lane8 * 4);
        float* dst = mat ? &Vs[row][lane8 * 4] : &Ks[row][lane8 * 4];
        *(float4*)dst = v;
      }
    }
  }
  __syncthreads();

  const int p  = t >> 2;
  const int tp = t & 3;
  const int pi = p >> 3, pj = p & 7;
  const int i = i0 + pi, j = j0 + pj;
  const int si = min(max(i - 3, 0), HH - KW);
  const int sj = min(max(j - 3, 0), WW - KW);
  const int lr0 = si - hs, lc0 = sj - ws;
  const int bi0 = si - i + (KW - 1);
  const int bj0 = sj - j + (KW - 1);

  float4 q[8];
  {
    const float* qp = qkv + (size_t)(i * WW + j) * 768 + head * HD;
#pragma unroll
    for (int z = 0; z < 8; ++z) q[z] = *(const float4*)(qp + z * 4);
  }

  const float scale = 0.17677669529663687f;
  const int nbeg = tp * 13;

  float lg[13];
#pragma unroll
  for (int z = 0; z < 13; ++z) lg[z] = -INFINITY;

#pragma unroll
  for (int z = 0; z < 13; ++z) {
    const int n = nbeg + z;
    if (n < KW * KW) {
      const int a = n / KW;
      const int c = n - a * KW;
      const int krow = (lr0 + a) * HALO + (lc0 + c);
      const float* kp = &Ks[krow][0];
      float s = 0.f;
#pragma unroll
      for (int zz = 0; zz < 8; ++zz) {
        const float4 kv = *(const float4*)(kp + zz * 4);
        s = fmaf(q[zz].x, kv.x, s);
        s = fmaf(q[zz].y, kv.y, s);
        s = fmaf(q[zz].z, kv.z, s);
        s = fmaf(q[zz].w, kv.w, s);
      }
      lg[z] = s * scale + Rs[(bi0 + a) * 13 + (bj0 + c)];
    }
  }

  float m = -INFINITY;
#pragma unroll
  for (int z = 0; z < 13; ++z) m = fmaxf(m, lg[z]);
  m = fmaxf(m, __shfl_xor(m, 1, 4));
  m = fmaxf(m, __shfl_xor(m, 2, 4));

  float ssum = 0.f;
#pragma unroll
  for (int z = 0; z < 13; ++z) {
    const float e = __expf(lg[z] - m);
    lg[z] = e;
    ssum += e;
  }
  ssum += __shfl_xor(ssum, 1, 4);
  ssum += __shfl_xor(ssum, 2, 4);
  const float inv = 1.f / ssum;

#pragma unroll
  for (int z = 0; z < 13; ++z) {
    const int n = nbeg + z;
    if (n < KW * KW) Ps[p][n] = lg[z] * inv;
  }
  __syncthreads();

  const int d0 = tp * 8;
  float4 o0 = {0.f, 0.f, 0.f, 0.f};
  float4 o1 = {0.f, 0.f, 0.f, 0.f};
#pragma unroll
  for (int a = 0; a < KW; ++a) {
    const int rbase = (lr0 + a) * HALO + lc0;
#pragma unroll
    for (int c = 0; c < KW; ++c) {
      const float pr = Ps[p][a * KW + c];
      const float* vp = &Vs[rbase + c][d0];
      const float4 va = *(const float4*)(vp);
      const float4 vb = *(const float4*)(vp + 4);
      o0.x = fmaf(pr, va.x, o0.x);
      o0.y = fmaf(pr, va.y, o0.y);
      o0.z = fmaf(pr, va.z, o0.z);
      o0.w = fmaf(pr, va.w, o0.w);
      o1.x = fmaf(pr, vb.x, o1.x);
      o1.y = fmaf(pr, vb.y, o1.y);
      o1.z = fmaf(pr, vb.z, o1.z);
      o1.w = fmaf(pr, vb.w, o1.w);
    }
  }

  ushort* op = aoutb + (size_t)(i * WW + j) * CC + head * HD + d0;
  ushort4 s0, s1;
  s0.x = f2bf(o0.x); s0.y = f2bf(o0.y); s0.z = f2bf(o0.z); s0.w = f2bf(o0.w);
  s1.x = f2bf(o1.x); s1.y = f2bf(o1.y); s1.z = f2bf(o1.z); s1.w = f2bf(o1.w);
  *(ushort4*)op       = s0;
  *(ushort4*)(op + 4) = s1;
}

extern "C" void kernel_launch(void* const* d_in, const int* in_sizes, int n_in,
                              void* d_out, int out_size, void* d_ws, size_t ws_size,
                              hipStream_t stream) {
  const float* x      = (const float*)d_in[0];
  const float* qkv_w  = (const float*)d_in[1];
  const float* qkv_b  = (const float*)d_in[2];
  const float* proj_w = (const float*)d_in[3];
  const float* proj_b = (const float*)d_in[4];
  const float* rpb    = (const float*)d_in[5];
  float* out = (float*)d_out;

  // workspace layout
  ushort* xb   = (ushort*)d_ws;            // 1,048,576 bf16
  ushort* qwb  = xb + 1048576;             // 196,608
  ushort* pwb  = qwb + 196608;             // 65,536
  float* qkv   = (float*)((char*)d_ws + 2621440);  // [4096,768] f32
  ushort* aoutb = (ushort*)(qkv + (size_t)NPIX * 768);  // [4096,256] bf16

  // 1) convert x, qkv_w, proj_w to bf16 (327,680 float4 tasks)
  convert_all<<<1280, 256, 0, stream>>>(x, qkv_w, proj_w, xb, qwb, pwb);

  // 2) QKV projection via MFMA: [4096,256]x[768,256]^T -> f32 [4096,768]
  gemm_mfma<768><<<dim3(64, 12), 256, 0, stream>>>(xb, qwb, qkv_b, qkv);

  // 3) neighborhood attention -> bf16 [4096,256]
  natten2<<<dim3(64, NHEAD), 256, 0, stream>>>(qkv, rpb, aoutb);

  // 4) output projection via MFMA -> f32 out
  gemm_mfma<256><<<dim3(64, 4), 256, 0, stream>>>(aoutb, pwb, proj_b, out);
}

// Round 4
// 47.439 us; speedup vs baseline: 2.5671x; 1.1198x over previous
//
#include <hip/hip_runtime.h>
#include <math.h>

#define HH 64
#define WW 64
#define CC 256
#define NHEAD 8
#define HD 32
#define KW 7
#define NPIX (HH * WW)

#define HALO 14
#define NROW 196       // 14*14
#define KROW 40        // K/V LDS row stride in ushorts (80 B, 16B-aligned)
#define PST 53         // probs stride (odd dwords -> banks spread)

typedef short short8v __attribute__((ext_vector_type(8)));
typedef float float4v __attribute__((ext_vector_type(4)));

__device__ __forceinline__ ushort f2bf(float f) {
  union { float f; unsigned u; } c;
  c.f = f;
  unsigned u = c.u;
  return (ushort)((u + 0x7FFFu + ((u >> 16) & 1u)) >> 16);
}
__device__ __forceinline__ float bflo(unsigned u) {
  union { unsigned i; float f; } c;
  c.i = u << 16;
  return c.f;
}
__device__ __forceinline__ float bfhi(unsigned u) {
  union { unsigned i; float f; } c;
  c.i = u & 0xFFFF0000u;
  return c.f;
}

// ---------------- f32 -> bf16 conversion for x, qkv_w, proj_w ----------------
__global__ __launch_bounds__(256) void convert_all(
    const float* __restrict__ x, const float* __restrict__ qw,
    const float* __restrict__ pw, ushort* __restrict__ xb,
    ushort* __restrict__ qwb, ushort* __restrict__ pwb) {
  const int i4 = blockIdx.x * 256 + threadIdx.x;
  const float* src;
  ushort* dst;
  int o4;
  if (i4 < 262144) {
    src = x; dst = xb; o4 = i4;
  } else if (i4 < 262144 + 49152) {
    src = qw; dst = qwb; o4 = i4 - 262144;
  } else {
    src = pw; dst = pwb; o4 = i4 - (262144 + 49152);
  }
  const float4 v = *(const float4*)(src + (size_t)o4 * 4);
  ushort4 o;
  o.x = f2bf(v.x); o.y = f2bf(v.y); o.z = f2bf(v.z); o.w = f2bf(v.w);
  *(ushort4*)(dst + (size_t)o4 * 4) = o;
}

// -------- LDS-tiled bf16 MFMA GEMM: C[M,N] = A[M,256] @ B[N,256]^T + bias ----
// 64x64 tile, K=256 staged whole (A,B panels are contiguous 32KB each).
// global_load_lds w=16 with XOR-swizzled SOURCE (linear LDS dest), swizzled
// ds_read -> 2-way max bank conflict. 4 waves x 32x32 out.
__device__ __forceinline__ short8v lds_frag(const char* base, int row, int kb) {
  const int lin = row * 512 + kb;
  const int swz = lin ^ ((row & 7) << 4);
  return *(const short8v*)(base + swz);
}

template <int N, bool OB>
__global__ __launch_bounds__(256, 2) void gemm_mfma2(
    const ushort* __restrict__ A, const ushort* __restrict__ B,
    const float* __restrict__ bias, void* __restrict__ Cd) {
  __shared__ ushort As[64 * 256];
  __shared__ ushort Bs[64 * 256];
  const int t = threadIdx.x;
  const int lane = t & 63;
  const int wave = t >> 6;
  const int bm = blockIdx.x * 64;
  const int bn = blockIdx.y * 64;

  const char* Ag = (const char*)(A + (size_t)bm * 256);
  const char* Bg = (const char*)(B + (size_t)bn * 256);
  char* Al = (char*)As;
  char* Bl = (char*)Bs;

#pragma unroll
  for (int it = 0; it < 8; ++it) {
    const int ls = it * 4096 + t * 16;
    const int gs = ls ^ (((ls >> 9) & 7) << 4);
    const int lb = it * 4096 + wave * 1024;  // wave-uniform base; HW adds lane*16
    __builtin_amdgcn_global_load_lds(
        (const __attribute__((address_space(1))) void*)(Ag + gs),
        (__attribute__((address_space(3))) void*)(Al + lb), 16, 0, 0);
    __builtin_amdgcn_global_load_lds(
        (const __attribute__((address_space(1))) void*)(Bg + gs),
        (__attribute__((address_space(3))) void*)(Bl + lb), 16, 0, 0);
  }
  __syncthreads();

  const int wr = (wave >> 1) * 32;
  const int wc = (wave & 1) * 32;
  const int lrow = lane & 15;
  const int lkb = (lane >> 4) * 16;  // byte offset of this lane's k-slice

  float4v acc[2][2] = {{{0.f, 0.f, 0.f, 0.f}, {0.f, 0.f, 0.f, 0.f}},
                       {{0.f, 0.f, 0.f, 0.f}, {0.f, 0.f, 0.f, 0.f}}};

#pragma unroll
  for (int ks = 0; ks < 8; ++ks) {
    const int kb = ks * 64 + lkb;
    const short8v a0 = lds_frag(Al, wr + lrow, kb);
    const short8v a1 = lds_frag(Al, wr + 16 + lrow, kb);
    const short8v b0 = lds_frag(Bl, wc + lrow, kb);
    const short8v b1 = lds_frag(Bl, wc + 16 + lrow, kb);
    acc[0][0] = __builtin_amdgcn_mfma_f32_16x16x32_bf16(a0, b0, acc[0][0], 0, 0, 0);
    acc[0][1] = __builtin_amdgcn_mfma_f32_16x16x32_bf16(a0, b1, acc[0][1], 0, 0, 0);
    acc[1][0] = __builtin_amdgcn_mfma_f32_16x16x32_bf16(a1, b0, acc[1][0], 0, 0, 0);
    acc[1][1] = __builtin_amdgcn_mfma_f32_16x16x32_bf16(a1, b1, acc[1][1], 0, 0, 0);
  }

#pragma unroll
  for (int bi = 0; bi < 2; ++bi) {
#pragma unroll
    for (int bj = 0; bj < 2; ++bj) {
      const int n = bn + wc + bj * 16 + lrow;
      const float bv = bias[n];
      const int m0 = bm + wr + bi * 16 + (lane >> 4) * 4;
      if (OB) {
        ushort* C = (ushort*)Cd;
#pragma unroll
        for (int r = 0; r < 4; ++r)
          C[(size_t)(m0 + r) * N + n] = f2bf(acc[bi][bj][r] + bv);
      } else {
        float* C = (float*)Cd;
#pragma unroll
        for (int r = 0; r < 4; ++r)
          C[(size_t)(m0 + r) * N + n] = acc[bi][bj][r] + bv;
      }
    }
  }
}

// ---------------- Tiled neighborhood attention, bf16 K/V/Q in LDS ------------
// grid (64 tiles of 8x8, 8 heads), 256 thr = 64 pixels x 4 lanes.
__global__ __launch_bounds__(256, 3) void natten3(
    const ushort* __restrict__ qkv, const float* __restrict__ rpb,
    ushort* __restrict__ aout) {
  __shared__ ushort Ks[NROW * KROW];
  __shared__ ushort Vs[NROW * KROW];
  __shared__ float Ps[64][PST];
  __shared__ float Rs[169];

  const int head = blockIdx.y;
  const int tile = blockIdx.x;
  const int i0 = (tile >> 3) * 8, j0 = (tile & 7) * 8;
  const int hs = min(max(i0 - 3, 0), HH - HALO);
  const int ws = min(max(j0 - 3, 0), WW - HALO);
  const int t = threadIdx.x;

  if (t < 169) Rs[t] = rpb[head * 169 + t];

  // stage K,V halo rows as bf16: 392 row-tasks, 4 lanes x 16B per row
  {
    const int lane4 = t & 3;
    const int r0 = t >> 2;  // 0..63
#pragma unroll
    for (int it = 0; it < 7; ++it) {
      const int task = it * 64 + r0;
      if (task < 2 * NROW) {
        const int mat = task >= NROW;
        const int row = task - mat * NROW;
        const int hr = row / HALO;
        const int hc = row - hr * HALO;
        const int g = (hs + hr) * WW + (ws + hc);
        const uint4 val = *(const uint4*)(qkv + (size_t)g * 768 + 256 + mat * 256 +
                                          head * HD + lane4 * 8);
        ushort* dst = (mat ? Vs : Ks) + row * KROW + lane4 * 8;
        *(uint4*)dst = val;
      }
    }
  }
  __syncthreads();

  const int p = t >> 2;
  const int tp = t & 3;
  const int i = i0 + (p >> 3), j = j0 + (p & 7);
  const int si = min(max(i - 3, 0), HH - KW);
  const int sj = min(max(j - 3, 0), WW - KW);
  const int lr0 = si - hs, lc0 = sj - ws;
  const int bi0 = si - i + (KW - 1);
  const int bj0 = sj - j + (KW - 1);

  // unpack q once, scale folded in
  float qf[32];
  {
    const ushort* qp = qkv + (size_t)(i * WW + j) * 768 + head * HD;
    const float scale = 0.17677669529663687f;  // 1/sqrt(32)
#pragma unroll
    for (int z = 0; z < 4; ++z) {
      const uint4 u = *(const uint4*)(qp + z * 8);
      qf[z * 8 + 0] = bflo(u.x) * scale;
      qf[z * 8 + 1] = bfhi(u.x) * scale;
      qf[z * 8 + 2] = bflo(u.y) * scale;
      qf[z * 8 + 3] = bfhi(u.y) * scale;
      qf[z * 8 + 4] = bflo(u.z) * scale;
      qf[z * 8 + 5] = bfhi(u.z) * scale;
      qf[z * 8 + 6] = bflo(u.w) * scale;
      qf[z * 8 + 7] = bfhi(u.w) * scale;
    }
  }

  const int nbeg = tp * 13;
  float lg[13];
#pragma unroll
  for (int z = 0; z < 13; ++z) lg[z] = -INFINITY;

#pragma unroll
  for (int z = 0; z < 13; ++z) {
    const int n = nbeg + z;
    if (n < KW * KW) {
      const int a = n / KW;
      const int c = n - a * KW;
      const int krow = (lr0 + a) * HALO + (lc0 + c);
      const ushort* kp = Ks + krow * KROW;
      float s = 0.f;
#pragma unroll
      for (int zz = 0; zz < 4; ++zz) {
        const uint4 k4 = *(const uint4*)(kp + zz * 8);
        s = fmaf(qf[zz * 8 + 0], bflo(k4.x), s);
        s = fmaf(qf[zz * 8 + 1], bfhi(k4.x), s);
        s = fmaf(qf[zz * 8 + 2], bflo(k4.y), s);
        s = fmaf(qf[zz * 8 + 3], bfhi(k4.y), s);
        s = fmaf(qf[zz * 8 + 4], bflo(k4.z), s);
        s = fmaf(qf[zz * 8 + 5], bfhi(k4.z), s);
        s = fmaf(qf[zz * 8 + 6], bflo(k4.w), s);
        s = fmaf(qf[zz * 8 + 7], bfhi(k4.w), s);
      }
      lg[z] = s + Rs[(bi0 + a) * 13 + (bj0 + c)];
    }
  }

  float m = -INFINITY;
#pragma unroll
  for (int z = 0; z < 13; ++z) m = fmaxf(m, lg[z]);
  m = fmaxf(m, __shfl_xor(m, 1, 4));
  m = fmaxf(m, __shfl_xor(m, 2, 4));

  float ssum = 0.f;
#pragma unroll
  for (int z = 0; z < 13; ++z) {
    const float e = __expf(lg[z] - m);
    lg[z] = e;
    ssum += e;
  }
  ssum += __shfl_xor(ssum, 1, 4);
  ssum += __shfl_xor(ssum, 2, 4);
  const float inv = 1.f / ssum;

#pragma unroll
  for (int z = 0; z < 13; ++z) {
    const int n = nbeg + z;
    if (n < KW * KW) Ps[p][n] = lg[z] * inv;
  }
  __syncthreads();

  // PV: thread owns 8 dims (tp*8), iterates 49 neighbors; V row-slice = 1 b128
  float o[8] = {0.f, 0.f, 0.f, 0.f, 0.f, 0.f, 0.f, 0.f};
#pragma unroll
  for (int a = 0; a < KW; ++a) {
    const int rbase = (lr0 + a) * HALO + lc0;
#pragma unroll
    for (int c = 0; c < KW; ++c) {
      const float pr = Ps[p][a * KW + c];
      const uint4 v4 = *(const uint4*)(Vs + (rbase + c) * KROW + tp * 8);
      o[0] = fmaf(pr, bflo(v4.x), o[0]);
      o[1] = fmaf(pr, bfhi(v4.x), o[1]);
      o[2] = fmaf(pr, bflo(v4.y), o[2]);
      o[3] = fmaf(pr, bfhi(v4.y), o[3]);
      o[4] = fmaf(pr, bflo(v4.z), o[4]);
      o[5] = fmaf(pr, bfhi(v4.z), o[5]);
      o[6] = fmaf(pr, bflo(v4.w), o[6]);
      o[7] = fmaf(pr, bfhi(v4.w), o[7]);
    }
  }

  const unsigned w0 = (unsigned)f2bf(o[0]) | ((unsigned)f2bf(o[1]) << 16);
  const unsigned w1 = (unsigned)f2bf(o[2]) | ((unsigned)f2bf(o[3]) << 16);
  const unsigned w2 = (unsigned)f2bf(o[4]) | ((unsigned)f2bf(o[5]) << 16);
  const unsigned w3 = (unsigned)f2bf(o[6]) | ((unsigned)f2bf(o[7]) << 16);
  uint4 st;
  st.x = w0; st.y = w1; st.z = w2; st.w = w3;
  *(uint4*)(aout + (size_t)(i * WW + j) * CC + head * HD + tp * 8) = st;
}

extern "C" void kernel_launch(void* const* d_in, const int* in_sizes, int n_in,
                              void* d_out, int out_size, void* d_ws, size_t ws_size,
                              hipStream_t stream) {
  const float* x      = (const float*)d_in[0];
  const float* qkv_w  = (const float*)d_in[1];
  const float* qkv_b  = (const float*)d_in[2];
  const float* proj_w = (const float*)d_in[3];
  const float* proj_b = (const float*)d_in[4];
  const float* rpb    = (const float*)d_in[5];
  float* out = (float*)d_out;

  // workspace layout (ushort elements)
  ushort* xb    = (ushort*)d_ws;            // 1,048,576
  ushort* qwb   = xb + 1048576;             // 196,608
  ushort* pwb   = qwb + 196608;             // 65,536
  ushort* qkvb  = pwb + 65536;              // 4096*768 = 3,145,728
  ushort* aoutb = qkvb + 3145728;           // 1,048,576

  // 1) convert x, qkv_w, proj_w to bf16
  convert_all<<<1280, 256, 0, stream>>>(x, qkv_w, proj_w, xb, qwb, pwb);

  // 2) QKV projection -> bf16 [4096,768]
  gemm_mfma2<768, true><<<dim3(64, 12), 256, 0, stream>>>(xb, qwb, qkv_b, qkvb);

  // 3) neighborhood attention -> bf16 [4096,256]
  natten3<<<dim3(64, NHEAD), 256, 0, stream>>>(qkvb, rpb, aoutb);

  // 4) output projection -> f32 out
  gemm_mfma2<256, false><<<dim3(64, 4), 256, 0, stream>>>(aoutb, pwb, proj_b, out);
}

// Round 5
// 35.104 us; speedup vs baseline: 3.4691x; 1.3514x over previous
//
#include <hip/hip_runtime.h>
#include <math.h>

#define HH 64
#define WW 64
#define CC 256
#define NHEAD 8
#define HD 32
#define KW 7
#define NPIX (HH * WW)

#define HALO_H 10
#define HALO_W 14
#define NROWH (HALO_H * HALO_W)  // 140
#define KROW 40                  // K/V LDS row stride in ushorts (80 B)
#define PST 51                   // probs stride (odd -> banks spread)

typedef short short8v __attribute__((ext_vector_type(8)));
typedef float float4v __attribute__((ext_vector_type(4)));

__device__ __forceinline__ ushort f2bf(float f) {
  union { float f; unsigned u; } c;
  c.f = f;
  unsigned u = c.u;
  return (ushort)((u + 0x7FFFu + ((u >> 16) & 1u)) >> 16);
}
__device__ __forceinline__ float bflo(unsigned u) {
  union { unsigned i; float f; } c;
  c.i = u << 16;
  return c.f;
}
__device__ __forceinline__ float bfhi(unsigned u) {
  union { unsigned i; float f; } c;
  c.i = u & 0xFFFF0000u;
  return c.f;
}

// ---------------- f32 -> bf16 conversion for x, qkv_w, proj_w ----------------
__global__ __launch_bounds__(256) void convert_all(
    const float* __restrict__ x, const float* __restrict__ qw,
    const float* __restrict__ pw, ushort* __restrict__ xb,
    ushort* __restrict__ qwb, ushort* __restrict__ pwb) {
  const int i4 = blockIdx.x * 256 + threadIdx.x;
  const float* src;
  ushort* dst;
  int o4;
  if (i4 < 262144) {
    src = x; dst = xb; o4 = i4;
  } else if (i4 < 262144 + 49152) {
    src = qw; dst = qwb; o4 = i4 - 262144;
  } else {
    src = pw; dst = pwb; o4 = i4 - (262144 + 49152);
  }
  const float4 v = *(const float4*)(src + (size_t)o4 * 4);
  ushort4 o;
  o.x = f2bf(v.x); o.y = f2bf(v.y); o.z = f2bf(v.z); o.w = f2bf(v.w);
  *(ushort4*)(dst + (size_t)o4 * 4) = o;
}

// -------- bf16 MFMA GEMM, K=256 in 4x64 chunks, double-buffered LDS ----------
// 64x64 tile, 4 waves x 32x32. LDS 32KB -> 5 blocks/CU. T3-lite 2-phase:
// issue next chunk's global_load_lds before computing current; one barrier
// per chunk (its vmcnt(0) drain lands after the compute).
template <int N, bool OB>
__global__ __launch_bounds__(256) void gemm_mfma3(
    const ushort* __restrict__ A, const ushort* __restrict__ B,
    const float* __restrict__ bias, void* __restrict__ Cd) {
  __shared__ ushort As[2][64 * 64];
  __shared__ ushort Bs[2][64 * 64];
  const int t = threadIdx.x;
  const int lane = t & 63;
  const int wave = t >> 6;
  const int bm = blockIdx.x * 64;
  const int bn = blockIdx.y * 64;

  const char* Ag = (const char*)(A + (size_t)bm * 256);
  const char* Bg = (const char*)(B + (size_t)bn * 256);

  // per-thread staging geometry (2 x 16B segments per matrix per chunk)
  const int ls0 = t * 16;               // 0..4095
  const int row0 = ls0 >> 7;            // /128B row
  const int ls1 = 4096 + t * 16;
  const int row1 = ls1 >> 7;
  const int lb0 = wave * 1024;          // wave-uniform LDS base (HW adds lane*16)
  const int lb1 = 4096 + wave * 1024;

#define STAGE(c, b)                                                            \
  {                                                                            \
    const int g0 = (row0 << 9) + (c) * 128 + ((ls0 & 127) ^ ((row0 & 7) << 4));\
    const int g1 = ((row1 & 31) << 9) + (c) * 128 +                            \
                   ((ls1 & 127) ^ ((row1 & 7) << 4));                          \
    __builtin_amdgcn_global_load_lds(                                          \
        (const __attribute__((address_space(1))) void*)(Ag + g0),              \
        (__attribute__((address_space(3))) void*)((char*)As[b] + lb0), 16, 0, 0);\
    __builtin_amdgcn_global_load_lds(                                          \
        (const __attribute__((address_space(1))) void*)(Ag + 16384 + g1),      \
        (__attribute__((address_space(3))) void*)((char*)As[b] + lb1), 16, 0, 0);\
    __builtin_amdgcn_global_load_lds(                                          \
        (const __attribute__((address_space(1))) void*)(Bg + g0),              \
        (__attribute__((address_space(3))) void*)((char*)Bs[b] + lb0), 16, 0, 0);\
    __builtin_amdgcn_global_load_lds(                                          \
        (const __attribute__((address_space(1))) void*)(Bg + 16384 + g1),      \
        (__attribute__((address_space(3))) void*)((char*)Bs[b] + lb1), 16, 0, 0);\
  }

  const int wr = (wave >> 1) * 32;
  const int wc = (wave & 1) * 32;
  const int lrow = lane & 15;
  const int lkb = (lane >> 4) * 16;

  float4v acc[2][2] = {{{0.f, 0.f, 0.f, 0.f}, {0.f, 0.f, 0.f, 0.f}},
                       {{0.f, 0.f, 0.f, 0.f}, {0.f, 0.f, 0.f, 0.f}}};

  STAGE(0, 0);
  __syncthreads();

#pragma unroll
  for (int c = 0; c < 4; ++c) {
    if (c < 3) STAGE(c + 1, (c + 1) & 1);
    const char* Al = (const char*)As[c & 1];
    const char* Bl = (const char*)Bs[c & 1];
#pragma unroll
    for (int ks = 0; ks < 2; ++ks) {
      const int kb = ks * 64 + lkb;
      const int a0r = (wr + lrow) * 128 + kb;
      const int a1r = (wr + 16 + lrow) * 128 + kb;
      const int b0r = (wc + lrow) * 128 + kb;
      const int b1r = (wc + 16 + lrow) * 128 + kb;
      const short8v a0 = *(const short8v*)(Al + (a0r ^ (((wr + lrow) & 7) << 4)));
      const short8v a1 = *(const short8v*)(Al + (a1r ^ (((wr + 16 + lrow) & 7) << 4)));
      const short8v b0 = *(const short8v*)(Bl + (b0r ^ (((wc + lrow) & 7) << 4)));
      const short8v b1 = *(const short8v*)(Bl + (b1r ^ (((wc + 16 + lrow) & 7) << 4)));
      acc[0][0] = __builtin_amdgcn_mfma_f32_16x16x32_bf16(a0, b0, acc[0][0], 0, 0, 0);
      acc[0][1] = __builtin_amdgcn_mfma_f32_16x16x32_bf16(a0, b1, acc[0][1], 0, 0, 0);
      acc[1][0] = __builtin_amdgcn_mfma_f32_16x16x32_bf16(a1, b0, acc[1][0], 0, 0, 0);
      acc[1][1] = __builtin_amdgcn_mfma_f32_16x16x32_bf16(a1, b1, acc[1][1], 0, 0, 0);
    }
    __syncthreads();
  }
#undef STAGE

#pragma unroll
  for (int bi = 0; bi < 2; ++bi) {
#pragma unroll
    for (int bj = 0; bj < 2; ++bj) {
      const int n = bn + wc + bj * 16 + lrow;
      const float bv = bias[n];
      const int m0 = bm + wr + bi * 16 + (lane >> 4) * 4;
      if (OB) {
        ushort* C = (ushort*)Cd;
#pragma unroll
        for (int r = 0; r < 4; ++r)
          C[(size_t)(m0 + r) * N + n] = f2bf(acc[bi][bj][r] + bv);
      } else {
        float* C = (float*)Cd;
#pragma unroll
        for (int r = 0; r < 4; ++r)
          C[(size_t)(m0 + r) * N + n] = acc[bi][bj][r] + bv;
      }
    }
  }
}

// ---------------- Tiled neighborhood attention, 4x8 tiles, 8 lanes/pixel -----
// grid (128 tiles, 8 heads) = 1024 blocks, ~30KB LDS -> 4+ blocks/CU resident.
__global__ __launch_bounds__(256) void natten4(
    const ushort* __restrict__ qkv, const float* __restrict__ rpb,
    ushort* __restrict__ aout) {
  __shared__ ushort Ks[NROWH * KROW];
  __shared__ ushort Vs[NROWH * KROW];
  __shared__ float Ps[32][PST];
  __shared__ float Rs[169];

  const int head = blockIdx.y;
  const int tile = blockIdx.x;
  const int i0 = (tile >> 3) * 4, j0 = (tile & 7) * 8;
  const int hs = min(max(i0 - 3, 0), HH - HALO_H);
  const int ws = min(max(j0 - 3, 0), WW - HALO_W);
  const int t = threadIdx.x;

  if (t < 169) Rs[t] = rpb[head * 169 + t];

  // stage K,V halo rows (bf16): 280 row-tasks, 4 lanes x 16B per row
  {
    const int lane4 = t & 3;
    const int r0 = t >> 2;  // 0..63
#pragma unroll
    for (int it = 0; it < 5; ++it) {
      const int task = it * 64 + r0;
      if (task < 2 * NROWH) {
        const int mat = task >= NROWH;
        const int row = task - mat * NROWH;
        const int hr = row / HALO_W;
        const int hc = row - hr * HALO_W;
        const int g = (hs + hr) * WW + (ws + hc);
        const uint4 val = *(const uint4*)(qkv + (size_t)g * 768 + 256 + mat * 256 +
                                          head * HD + lane4 * 8);
        ushort* dst = (mat ? Vs : Ks) + row * KROW + lane4 * 8;
        *(uint4*)dst = val;
      }
    }
  }
  __syncthreads();

  const int p = t >> 3;   // pixel 0..31
  const int tp = t & 7;   // lane within pixel
  const int i = i0 + (p >> 3), j = j0 + (p & 7);
  const int si = min(max(i - 3, 0), HH - KW);
  const int sj = min(max(j - 3, 0), WW - KW);
  const int lr0 = si - hs, lc0 = sj - ws;
  const int bi0 = si - i + (KW - 1);
  const int bj0 = sj - j + (KW - 1);

  // unpack q once, scale folded in
  float qf[32];
  {
    const ushort* qp = qkv + (size_t)(i * WW + j) * 768 + head * HD;
    const float scale = 0.17677669529663687f;  // 1/sqrt(32)
#pragma unroll
    for (int z = 0; z < 4; ++z) {
      const uint4 u = *(const uint4*)(qp + z * 8);
      qf[z * 8 + 0] = bflo(u.x) * scale;
      qf[z * 8 + 1] = bfhi(u.x) * scale;
      qf[z * 8 + 2] = bflo(u.y) * scale;
      qf[z * 8 + 3] = bfhi(u.y) * scale;
      qf[z * 8 + 4] = bflo(u.z) * scale;
      qf[z * 8 + 5] = bfhi(u.z) * scale;
      qf[z * 8 + 6] = bflo(u.w) * scale;
      qf[z * 8 + 7] = bfhi(u.w) * scale;
    }
  }

  // QK: each lane owns 7 of 49 neighbors
  const int nbeg = tp * 7;
  float lg[7];
#pragma unroll
  for (int z = 0; z < 7; ++z) lg[z] = -INFINITY;

#pragma unroll
  for (int z = 0; z < 7; ++z) {
    const int n = nbeg + z;
    if (n < KW * KW) {
      const int a = n / KW;
      const int c = n - a * KW;
      const int krow = (lr0 + a) * HALO_W + (lc0 + c);
      const ushort* kp = Ks + krow * KROW;
      float s = 0.f;
#pragma unroll
      for (int zz = 0; zz < 4; ++zz) {
        const uint4 k4 = *(const uint4*)(kp + zz * 8);
        s = fmaf(qf[zz * 8 + 0], bflo(k4.x), s);
        s = fmaf(qf[zz * 8 + 1], bfhi(k4.x), s);
        s = fmaf(qf[zz * 8 + 2], bflo(k4.y), s);
        s = fmaf(qf[zz * 8 + 3], bfhi(k4.y), s);
        s = fmaf(qf[zz * 8 + 4], bflo(k4.z), s);
        s = fmaf(qf[zz * 8 + 5], bfhi(k4.z), s);
        s = fmaf(qf[zz * 8 + 6], bflo(k4.w), s);
        s = fmaf(qf[zz * 8 + 7], bfhi(k4.w), s);
      }
      lg[z] = s + Rs[(bi0 + a) * 13 + (bj0 + c)];
    }
  }

  float m = -INFINITY;
#pragma unroll
  for (int z = 0; z < 7; ++z) m = fmaxf(m, lg[z]);
  m = fmaxf(m, __shfl_xor(m, 1, 8));
  m = fmaxf(m, __shfl_xor(m, 2, 8));
  m = fmaxf(m, __shfl_xor(m, 4, 8));

  float ssum = 0.f;
#pragma unroll
  for (int z = 0; z < 7; ++z) {
    const float e = __expf(lg[z] - m);  // exp(-inf)=0 for padding
    lg[z] = e;
    ssum += e;
  }
  ssum += __shfl_xor(ssum, 1, 8);
  ssum += __shfl_xor(ssum, 2, 8);
  ssum += __shfl_xor(ssum, 4, 8);
  const float inv = 1.f / ssum;

#pragma unroll
  for (int z = 0; z < 7; ++z) {
    const int n = nbeg + z;
    if (n < KW * KW) Ps[p][n] = lg[z] * inv;
  }
  __syncthreads();

  // PV: lanes split neighbors in halves (25/24), each owns 8 dims
  const int half = tp >> 2;
  const int d0 = (tp & 3) * 8;
  float o[8] = {0.f, 0.f, 0.f, 0.f, 0.f, 0.f, 0.f, 0.f};
#pragma unroll
  for (int z = 0; z < 25; ++z) {
    const int n = half * 25 + z;
    if (n < KW * KW) {
      const int a = n / KW;
      const int c = n - a * KW;
      const float pr = Ps[p][n];
      const int vrow = (lr0 + a) * HALO_W + (lc0 + c);
      const uint4 v4 = *(const uint4*)(Vs + vrow * KROW + d0);
      o[0] = fmaf(pr, bflo(v4.x), o[0]);
      o[1] = fmaf(pr, bfhi(v4.x), o[1]);
      o[2] = fmaf(pr, bflo(v4.y), o[2]);
      o[3] = fmaf(pr, bfhi(v4.y), o[3]);
      o[4] = fmaf(pr, bflo(v4.z), o[4]);
      o[5] = fmaf(pr, bfhi(v4.z), o[5]);
      o[6] = fmaf(pr, bflo(v4.w), o[6]);
      o[7] = fmaf(pr, bfhi(v4.w), o[7]);
    }
  }
  // combine the two neighbor-halves (lane ^ 4)
#pragma unroll
  for (int z = 0; z < 8; ++z) o[z] += __shfl_xor(o[z], 4, 8);

  if ((tp & 4) == 0) {
    const unsigned w0 = (unsigned)f2bf(o[0]) | ((unsigned)f2bf(o[1]) << 16);
    const unsigned w1 = (unsigned)f2bf(o[2]) | ((unsigned)f2bf(o[3]) << 16);
    const unsigned w2 = (unsigned)f2bf(o[4]) | ((unsigned)f2bf(o[5]) << 16);
    const unsigned w3 = (unsigned)f2bf(o[6]) | ((unsigned)f2bf(o[7]) << 16);
    uint4 st;
    st.x = w0; st.y = w1; st.z = w2; st.w = w3;
    *(uint4*)(aout + (size_t)(i * WW + j) * CC + head * HD + d0) = st;
  }
}

extern "C" void kernel_launch(void* const* d_in, const int* in_sizes, int n_in,
                              void* d_out, int out_size, void* d_ws, size_t ws_size,
                              hipStream_t stream) {
  const float* x      = (const float*)d_in[0];
  const float* qkv_w  = (const float*)d_in[1];
  const float* qkv_b  = (const float*)d_in[2];
  const float* proj_w = (const float*)d_in[3];
  const float* proj_b = (const float*)d_in[4];
  const float* rpb    = (const float*)d_in[5];
  float* out = (float*)d_out;

  // workspace layout (ushort elements)
  ushort* xb    = (ushort*)d_ws;            // 1,048,576
  ushort* qwb   = xb + 1048576;             // 196,608
  ushort* pwb   = qwb + 196608;             // 65,536
  ushort* qkvb  = pwb + 65536;              // 4096*768
  ushort* aoutb = qkvb + 3145728;           // 4096*256

  convert_all<<<1280, 256, 0, stream>>>(x, qkv_w, proj_w, xb, qwb, pwb);

  gemm_mfma3<768, true><<<dim3(64, 12), 256, 0, stream>>>(xb, qwb, qkv_b, qkvb);

  natten4<<<dim3(128, NHEAD), 256, 0, stream>>>(qkvb, rpb, aoutb);

  gemm_mfma3<256, false><<<dim3(64, 4), 256, 0, stream>>>(aoutb, pwb, proj_b, out);
}